// Round 9
// baseline (167.608 us; speedup 1.0000x reference)
//
#include <hip/hip_runtime.h>
#include <hip/hip_bf16.h>
#include <math.h>

#define NCLS 80
#define TOPK_N 1000
#define CAND_CAP 12288
#define T0 0.91f                // fast-path score threshold (exactness gated)
#define OBJ_T 1.55f             // obj pre-filter: sig(1.55)=0.8249 < T0^2=0.8281
                                // score>T0 ==> sig(obj)>T0^2 ==> obj>OBJ_T (safe margin)
#define NB 8192                 // fallback histogram bins = score_bits >> 17
#define RBINS 3072              // rank bins (counting sort)
#define RBIN_LO 0x3F680000u     // float bits of ~0.90625
#define ANCH_INV 524287         // 2^19-1, anchor < 300000

// ---- workspace layout (bytes), M = 300000 ----
#define WS_CAND     0           // 12288 u64 composite keys (98304 B)
#define WS_TKSCORE  98304       // 1000 f32
#define WS_TKLABEL  102304      // 1000 i32
#define WS_BOXES    106304      // 1000 float4
#define WS_OBX      122304      // 1000 float4 (class-offset boxes)
#define WS_AREAS    138304      // 1000 f32
#define WS_MASK     142304      // 1000 * 16 u64 transposed sup mask (128000 B)
#define WS_META     270304      // [2]=fast-path candidate counter (64 B zeroed)
// end = 270,368 B

typedef unsigned long long u64;

__device__ __forceinline__ float sigmoidf_(float x) {
    return 1.0f / (1.0f + expf(-x));
}

// composite key: [57:26]=score bits, [25:7]=(2^19-1-anchor), [6:0]=label.
// u64 descending == (score desc, anchor asc); (score,anchor) unique, so the
// label bits never decide an ordering comparison.
__device__ __forceinline__ u64 make_key3(unsigned s32, int anchor, int label) {
    return ((u64)s32 << 26)
         | ((u64)(unsigned)(ANCH_INV - anchor) << 7)
         | (unsigned)label;
}

// BIN 0 = HIGHEST scores (descending bins): ascending-bin exclusive prefix
// sum = "# elements in higher-score bins" = correct rank base.
__device__ __forceinline__ int key_bin(u64 k) {
    unsigned s32 = (unsigned)(k >> 26);
    int d = (int)(s32 - RBIN_LO);
    if (d < 0) d = 0;
    int b = d >> 9;
    if (b > RBINS - 1) b = RBINS - 1;
    return (RBINS - 1) - b;
}

// row max+argmax over 80 classes with 16 lanes (l = lane & 15), first-max tie
__device__ __forceinline__ void rowmax16(const float4* row, int l,
                                         float& bv, int& bc) {
    float4 v4 = row[l];
    bv = v4.x; bc = l * 4;
    if (v4.y > bv) { bv = v4.y; bc = l * 4 + 1; }
    if (v4.z > bv) { bv = v4.z; bc = l * 4 + 2; }
    if (v4.w > bv) { bv = v4.w; bc = l * 4 + 3; }
    if (l < 4) {
        float4 w4 = row[16 + l];
        int cb = 64 + l * 4;
        if (w4.x > bv) { bv = w4.x; bc = cb; }
        if (w4.y > bv) { bv = w4.y; bc = cb + 1; }
        if (w4.z > bv) { bv = w4.z; bc = cb + 2; }
        if (w4.w > bv) { bv = w4.w; bc = cb + 3; }
    }
    #pragma unroll
    for (int m = 8; m >= 1; m >>= 1) {
        float ov = __shfl_xor(bv, m);
        int oc = __shfl_xor(bc, m);
        if (ov > bv || (ov == bv && oc < bc)) { bv = ov; bc = oc; }
    }
}

// K1 (fast path): coalesced per-lane obj scan (256 anchors/block),
// survivors to LDS queue, 16-lane groups drain queue for cls row max+argmax.
// score>T0 requires sig(obj)>T0^2 (since sig(clsmax)<1) => obj>OBJ_T is a
// strictly looser necessary condition -> candidate set {score>T0} unchanged.
// Label rides in the key's low bits so no later kernel re-reads cls.
__global__ void __launch_bounds__(256)
k1_scores(const float* __restrict__ obj,
          const float* __restrict__ cls,
          u64* __restrict__ cand,
          int* __restrict__ counter,
          int M) {
    __shared__ int lcount, lbase, nsurv;
    __shared__ int sanch[256];
    __shared__ float sobj[256];
    __shared__ u64 lkeys[256];
    int t = threadIdx.x;
    if (t == 0) { lcount = 0; nsurv = 0; }
    __syncthreads();
    int a = blockIdx.x * 256 + t;
    float o = (a < M) ? obj[a] : -1e30f;       // coalesced 1KB/wave
    if (o > OBJ_T) {
        int p = atomicAdd(&nsurv, 1);
        sanch[p] = a; sobj[p] = o;
    }
    __syncthreads();
    int ns = nsurv;                            // ~5.8% of 256 ~= 15 expected
    int grp = t >> 4, l = t & 15;
    for (int s = grp; s < ns; s += 16) {       // uniform per 16-lane group
        int anchor = sanch[s];
        const float4* p = (const float4*)(cls + (size_t)anchor * NCLS);
        float bv; int bc;
        rowmax16(p, l, bv, bc);                // same loads, + argmax track
        if (l == 0) {
            float score = sqrtf(sigmoidf_(sobj[s]) * sigmoidf_(bv));
            if (score > T0) {
                int pos = atomicAdd(&lcount, 1);
                lkeys[pos] = make_key3(__float_as_uint(score), anchor, bc);
            }
        }
    }
    __syncthreads();
    if (t == 0 && lcount > 0) lbase = atomicAdd(counter, lcount);
    __syncthreads();
    int n = lcount;
    if (t < n) {
        int pos = lbase + t;
        if (pos < CAND_CAP) cand[pos] = lkeys[t];
    }
}

// K4R (single block): counting-sort rank -> tkscore + in-block gather tail
// (label decoded from key; one fully-parallel scattered box load per rank —
// no per-rank cls re-read, no extra kernel).
// Gated in-block fallback (never taken on this data, exact): LDS histogram
// over all M scores (aliases sorted[]), descending scan -> bin B, compact
// to cand with LDS counter — all __syncthreads, no device fences.
__global__ void __launch_bounds__(1024)
k4r_rank(const float* __restrict__ obj,
         const float* __restrict__ cls,
         const float4* __restrict__ box,
         u64* __restrict__ cand,
         const int* __restrict__ meta,
         float* __restrict__ tkscore,
         int* __restrict__ tklabel,
         float4* __restrict__ boxes_k,
         float4* __restrict__ obx,
         float* __restrict__ areas,
         int M) {
    __shared__ u64 sorted[CAND_CAP];        // 98304 B (fallback hist aliases)
    __shared__ unsigned hist[RBINS];
    __shared__ unsigned cnt[RBINS];
    __shared__ unsigned wsum[16], woff[16];
    __shared__ int ranchlab[TOPK_N];        // (anch_inv<<7)|label per rank
    __shared__ int fbB, fbC;
    int t = threadIdx.x;                    // 1024
    int lane = t & 63, w = t >> 6;
    int Cf = meta[2];
    bool fast = (Cf >= TOPK_N && Cf <= CAND_CAP);
    int C;
    if (fast) {
        C = Cf;
    } else {
        // ---------- in-block exact fallback ----------
        unsigned* fh = (unsigned*)sorted;   // 8192 u32 = 32 KB alias
        for (int b = t; b < NB; b += 1024) fh[b] = 0;
        if (t == 0) { fbB = 0; fbC = 0; }
        __syncthreads();
        int g = t >> 4, l = t & 15;         // 64 groups of 16 lanes
        for (int a0 = g; a0 < M; a0 += 64) {
            const float4* row = (const float4*)(cls + (size_t)a0 * NCLS);
            float bv; int bc;
            rowmax16(row, l, bv, bc);
            if (l == 0) {
                float sc = sqrtf(sigmoidf_(obj[a0]) * sigmoidf_(bv));
                atomicAdd(&fh[__float_as_uint(sc) >> 17], 1u);
            }
        }
        __syncthreads();
        // descending scan: thread t covers 8 bins from the top
        int base = NB - 1 - t * 8;
        unsigned bins[8]; unsigned s = 0;
        #pragma unroll
        for (int k = 0; k < 8; ++k) { unsigned h = fh[base - k]; bins[k] = h; s += h; }
        unsigned inc = s;
        for (int d = 1; d < 64; d <<= 1) {
            unsigned pv = __shfl_up(inc, d);
            if (lane >= d) inc += pv;
        }
        if (lane == 63) wsum[w] = inc;
        __syncthreads();
        if (t == 0) {
            unsigned cum = 0;
            for (int i = 0; i < 16; ++i) { woff[i] = cum; cum += wsum[i]; }
        }
        __syncthreads();
        unsigned excl = woff[w] + inc - s;
        if (excl < TOPK_N && excl + s >= TOPK_N) {
            unsigned cum = excl; int b = base;
            #pragma unroll
            for (int k = 0; k < 8; ++k) {
                unsigned h = bins[k];
                if (cum + h >= TOPK_N) { fbB = b; break; }
                cum += h; --b;
            }
        }
        __syncthreads();
        int B = fbB;
        for (int a0 = g; a0 < M; a0 += 64) {
            const float4* row = (const float4*)(cls + (size_t)a0 * NCLS);
            float bv; int bc;
            rowmax16(row, l, bv, bc);
            if (l == 0) {
                float sc = sqrtf(sigmoidf_(obj[a0]) * sigmoidf_(bv));
                unsigned key = __float_as_uint(sc);
                if ((int)(key >> 17) >= B) {
                    int pos = atomicAdd(&fbC, 1);
                    if (pos < CAND_CAP) cand[pos] = make_key3(key, a0, bc);
                }
            }
        }
        __syncthreads();
        C = fbC < CAND_CAP ? fbC : CAND_CAP;
        __syncthreads();                    // fh alias dead before sort reuse
    }
    // ---------- counting-sort rank ----------
    for (int b = t; b < RBINS; b += 1024) { hist[b] = 0; cnt[b] = 0; }
    __syncthreads();
    u64 keys[12]; int nk = 0;
    for (int i = t; i < C; i += 1024) {
        u64 k = cand[i];
        keys[nk++] = k;
        atomicAdd(&hist[key_bin(k)], 1u);
    }
    __syncthreads();
    unsigned h0 = hist[t * 3], h1 = hist[t * 3 + 1], h2 = hist[t * 3 + 2];
    unsigned s2 = h0 + h1 + h2;
    unsigned inc2 = s2;
    for (int d = 1; d < 64; d <<= 1) {
        unsigned pv = __shfl_up(inc2, d);
        if (lane >= d) inc2 += pv;
    }
    if (lane == 63) wsum[w] = inc2;
    __syncthreads();
    if (t == 0) {
        unsigned cum = 0;
        for (int i = 0; i < 16; ++i) { woff[i] = cum; cum += wsum[i]; }
    }
    __syncthreads();
    unsigned rbase = woff[w] + inc2 - s2;
    hist[t * 3] = rbase;
    hist[t * 3 + 1] = rbase + h0;
    hist[t * 3 + 2] = rbase + h0 + h1;
    __syncthreads();
    nk = 0;
    for (int i = t; i < C; i += 1024) {
        u64 k = keys[nk++];
        int b = key_bin(k);
        unsigned pos = hist[b] + atomicAdd(&cnt[b], 1u);
        sorted[pos] = k;
    }
    __syncthreads();
    for (int p = t; p < C; p += 1024) {
        u64 k = sorted[p];
        int b = key_bin(k);
        unsigned b0 = hist[b], b1 = b0 + cnt[b];
        int r = (int)b0;
        for (unsigned q = b0; q < b1; ++q) r += (sorted[q] > k);
        if (r < TOPK_N) {
            tkscore[r] = __uint_as_float((unsigned)(k >> 26));
            ranchlab[r] = (int)(unsigned)(k & 0x3FFFFFF);  // [25:7]=anch_inv,[6:0]=label
        }
    }
    __syncthreads();
    // ---------- gather tail: 1000 parallel ranks, ONE iteration ----------
    if (t < TOPK_N) {
        int al = ranchlab[t];
        int anchor = ANCH_INV - ((al >> 7) & 0x7FFFF);
        int lab = al & 0x7F;
        tklabel[t] = lab;
        float4 b = box[anchor];
        boxes_k[t] = b;
        float off = (float)lab * 4096.0f;
        float4 ob = make_float4(b.x + off, b.y + off, b.z + off, b.w + off);
        obx[t] = ob;
        areas[t] = fmaxf(ob.z - ob.x, 0.0f) * fmaxf(ob.w - ob.y, 0.0f);
    }
}

// K5: transposed suppression mask with block-local LDS staging of all
// obx/areas (20 KB); 16 rows/block (one per wave), 63 blocks.
__global__ void __launch_bounds__(1024)
k5_iou(const float4* __restrict__ obx,
       const float* __restrict__ areas,
       u64* __restrict__ mask) {
    __shared__ float4 sobx[TOPK_N];         // 16000 B
    __shared__ float  sarea[TOPK_N];        // 4000 B
    int t = threadIdx.x;
    for (int j = t; j < TOPK_N; j += 1024) { sobx[j] = obx[j]; sarea[j] = areas[j]; }
    __syncthreads();
    int w = t >> 6, lane = t & 63;
    int i = blockIdx.x * 16 + w;
    if (i >= TOPK_N) return;
    float4 bi = sobx[i];
    float ai = sarea[i];
    #pragma unroll 4
    for (int q = 0; q < 16; ++q) {
        int c = q * 64 + lane;
        bool bit = false;
        if (c < i) {
            float4 bc = sobx[c];
            float xx1 = fmaxf(bi.x, bc.x), yy1 = fmaxf(bi.y, bc.y);
            float xx2 = fminf(bi.z, bc.z), yy2 = fminf(bi.w, bc.w);
            float inter = fmaxf(xx2 - xx1, 0.0f) * fmaxf(yy2 - yy1, 0.0f);
            float iou = inter / (ai + sarea[c] - inter + 1e-9f);
            bit = iou > 0.5f;
        }
        u64 bal = __ballot(bit);
        if (lane == 0) mask[(size_t)i * 16 + q] = bal;
    }
}

// K6: atomic-free parallel exact greedy NMS + fused output write.
__global__ void __launch_bounds__(1024)
k6_nms(const float* __restrict__ tkscore,
       const u64* __restrict__ mask,
       const int* __restrict__ tklabel,
       const float4* __restrict__ boxes_k,
       float* __restrict__ out) {
    __shared__ u64 kept_s[16], dec_s[16];
    int t = threadIdx.x, w = t >> 6, lane = t & 63;
    bool active = t < TOPK_N;
    u64 sup[16];
    float sc = 0.0f;
    if (active) {
        #pragma unroll
        for (int q = 0; q < 16; ++q) sup[q] = mask[(size_t)t * 16 + q];
        sc = tkscore[t];
    } else {
        #pragma unroll
        for (int q = 0; q < 16; ++q) sup[q] = 0ULL;
    }
    bool conf = active && (sc > 0.001f);
    bool mydec = !conf;
    bool mykept = false;
    u64 db = __ballot(mydec), kb = __ballot(mykept);
    if (lane == 0) { dec_s[w] = db; kept_s[w] = kb; }
    __syncthreads();
    for (int round = 0; round < TOPK_N; ++round) {
        if (!mydec) {
            u64 pend = 0;
            #pragma unroll
            for (int q = 0; q < 16; ++q) pend |= sup[q] & ~dec_s[q];
            if (pend == 0ULL) {
                u64 kk = 0;
                #pragma unroll
                for (int q = 0; q < 16; ++q) kk |= sup[q] & kept_s[q];
                mydec = true; mykept = (kk == 0ULL);
            }
        }
        __syncthreads();
        db = __ballot(mydec); kb = __ballot(mykept);
        if (lane == 0) { dec_s[w] = db; kept_s[w] = kb; }
        __syncthreads();
        u64 a = ~0ULL;
        #pragma unroll
        for (int q = 0; q < 16; ++q) a &= dec_s[q];
        if (a == ~0ULL) break;
    }
    if (active) {
        float k = mykept ? 1.0f : 0.0f;
        float4 b = boxes_k[t];
        out[t * 5 + 0] = sc * k;
        out[t * 5 + 1] = b.x * k;
        out[t * 5 + 2] = b.y * k;
        out[t * 5 + 3] = b.z * k;
        out[t * 5 + 4] = b.w * k;
        out[5 * TOPK_N + t] = (float)tklabel[t];
        out[6 * TOPK_N + t] = k;
    }
}

extern "C" void kernel_launch(void* const* d_in, const int* in_sizes, int n_in,
                              void* d_out, int out_size, void* d_ws, size_t ws_size,
                              hipStream_t stream) {
    const float* obj = (const float*)d_in[0];
    const float* cls = (const float*)d_in[1];
    const float* box = (const float*)d_in[2];
    float* out = (float*)d_out;
    char* ws = (char*)d_ws;
    int M = in_sizes[0];   // 300000

    u64*      cand    = (u64*)(ws + WS_CAND);
    float*    tkscore = (float*)(ws + WS_TKSCORE);
    int*      tklabel = (int*)(ws + WS_TKLABEL);
    float4*   boxes_k = (float4*)(ws + WS_BOXES);
    float4*   obx     = (float4*)(ws + WS_OBX);
    float*    areas   = (float*)(ws + WS_AREAS);
    u64*      mask    = (u64*)(ws + WS_MASK);
    int*      meta    = (int*)(ws + WS_META);

    // zero meta only (64 B)
    hipMemsetAsync(ws + WS_META, 0, 64, stream);

    k1_scores<<<(M + 255) / 256, 256, 0, stream>>>(obj, cls, cand, meta + 2, M);
    k4r_rank<<<1, 1024, 0, stream>>>(obj, cls, (const float4*)box, cand, meta,
                                     tkscore, tklabel, boxes_k, obx, areas, M);
    k5_iou<<<63, 1024, 0, stream>>>(obx, areas, mask);
    k6_nms<<<1, 1024, 0, stream>>>(tkscore, mask, tklabel, boxes_k, out);
}